// Round 1
// baseline (2563.876 us; speedup 1.0000x reference)
//
#include <hip/hip_runtime.h>
#include <stdint.h>

// ---------------- problem constants ----------------
#define NSTEP 100
#define BSZ   256
#define FEAT  1024
#define WPAD  1032   // padded K stride (bf16 elems) for LDS weight tiles

typedef __attribute__((ext_vector_type(8))) short short8;
typedef __attribute__((ext_vector_type(4))) float floatx4;

// ---------------- workspace layout (bytes) ----------------
#define OFF_EC3   0u                         // 2*256*1024*2 = 1 MB (parity dbuf, bf16)
#define OFF_CA1   (1u << 20)                 // 1 MB
#define OFF_DRIVE (2u << 20)                 // 100*1024*4 = 400 KB
#define OFF_EC3F  (OFF_DRIVE + (512u << 10)) // 8*32 int flags
#define OFF_CA1F  (OFF_EC3F + 4096u)
#define OFF_DRVF  (OFF_CA1F + 4096u)
#define WS_NEED   (OFF_DRVF + 4096u)

// ---------------- output layout (float elems) ----------------
#define O_ACT 0
#define O_E3H 512
#define O_E5H (512 + 102400)
#define O_CAH (512 + 204800)
#define O_E3  (512 + 307200)
#define O_E5  (O_E3 + 262144)
#define O_CA  (O_E5 + 262144)

// ---------------- LDS layout (bytes) ----------------
#define LDS_W1   0
#define LDS_W2   66048                 // 32*1032*2
#define LDS_DRV  132096                // 100*32*4 = 12800
#define LDS_RED  (132096 + 12800)      // 8*32*4 = 1024
#define LDS_ACT  (LDS_RED + 1024)      // 32*2*4 = 256
#define LDS_TOTAL (LDS_ACT + 256)      // 146176 < 163840

__device__ __forceinline__ short f2bf(float x) {
  uint32_t u = __builtin_bit_cast(uint32_t, x);
  uint32_t r = (u + 0x7FFFu + ((u >> 16) & 1u)) >> 16;   // RNE
  return (short)r;
}
__device__ __forceinline__ float sigm(float x) { return 1.0f / (1.0f + __expf(-x)); }

__device__ __forceinline__ floatx4 mfma16(short8 a, short8 b, floatx4 c) {
  return __builtin_amdgcn_mfma_f32_16x16x32_bf16(a, b, c, 0, 0, 0);
}

extern "C" __global__ void __launch_bounds__(256)
hpcrnn_kernel(const int* __restrict__ cue,
              const float* __restrict__ ec3_last,
              const float* __restrict__ ec5_last,
              const float* __restrict__ ca1bias,
              const float* __restrict__ wca3ca1,
              const float* __restrict__ wec3ca1,
              const float* __restrict__ wca1ec5,
              const float* __restrict__ wca1act,
              const float* __restrict__ actbias,
              float* __restrict__ out,
              char* __restrict__ ws)
{
  extern __shared__ __attribute__((aligned(16))) char lds[];
  short* w1l    = (short*)(lds + LDS_W1);   // [32][WPAD] bf16: w1[:,C+n] transposed
  short* w2l    = (short*)(lds + LDS_W2);
  float* drv    = (float*)(lds + LDS_DRV);  // [100][32]
  float* red    = (float*)(lds + LDS_RED);  // [8][32]
  float* actred = (float*)(lds + LDS_ACT);  // [32][2]

  const int tid = threadIdx.x;
  const int bi  = blockIdx.x & 7;    // batch group (32 rows) -- %8 to keep groups XCD-local
  const int nj  = blockIdx.x >> 3;   // N chunk (32 cols)
  const int R   = bi * 32, C = nj * 32;

  short* ec3buf = (short*)(ws + OFF_EC3);
  short* ca1buf = (short*)(ws + OFF_CA1);
  float* driveg = (float*)(ws + OFF_DRIVE);
  int*   ec3flag = (int*)(ws + OFF_EC3F);
  int*   ca1flag = (int*)(ws + OFF_CA1F);
  int*   drvflag = (int*)(ws + OFF_DRVF);

  // ---- weights -> LDS, bf16, transposed to [n_local][k] ----
  {
    const int c = tid & 31;
    for (int k = tid >> 5; k < FEAT; k += 8) {
      w1l[c * WPAD + k] = f2bf(wec3ca1[k * FEAT + C + c]);
      w2l[c * WPAD + k] = f2bf(wca1ec5[k * FEAT + C + c]);
    }
  }
  if (tid < 64) actred[tid] = 0.0f;

  // ---- drive precompute: this block does t === bi (mod 8), cols C..C+31 ----
  {
    const int g = tid >> 5, n = tid & 31;
    for (int t = bi; t < NSTEP; t += 8) {
      float part = 0.0f;
      const float tf = (float)t;
      for (int c = g * 128; c < g * 128 + 128; ++c) {
        float d = (float)c * (100.0f / 1023.0f) - tf;
        part += __expf(d * d * -0.02f) * wca3ca1[c * FEAT + C + n];
      }
      __syncthreads();
      red[g * 32 + n] = part;
      __syncthreads();
      if (g == 0) {
        float s = 0.0f;
#pragma unroll
        for (int gg = 0; gg < 8; ++gg) s += red[gg * 32 + n];
        driveg[t * FEAT + C + n] = s;
      }
    }
    __syncthreads();
    if (tid == 0) {
      __builtin_amdgcn_fence(__ATOMIC_RELEASE, "agent");
      __hip_atomic_fetch_add(&drvflag[nj], 1, __ATOMIC_RELAXED, __HIP_MEMORY_SCOPE_AGENT);
    }
  }

  // ---- per-lane geometry (MFMA C-layout: col=lane&15, row=4*quad+reg) ----
  const int w  = tid >> 6, l = tid & 63;
  const int fr = w >> 1, fc = w & 1;      // 16x16 fragment coords in 32x32 tile
  const int lc = l & 15, q = l >> 4;
  const int cg = C + 16 * fc + lc;        // state/global column
  const int r0 = R + 16 * fr + 4 * q;     // state row base (4 rows)
  const int rA = R + 16 * fr + lc;        // A-operand row (A: m=lane&15)
  const int kq = q * 8;                   // A/B k sub-offset

  float ec5s[4], ec3s[4], ca1s[4];
#pragma unroll
  for (int i = 0; i < 4; ++i) {
    ec5s[i] = ec5_last[(r0 + i) * FEAT + cg];
    ec3s[i] = ec3_last[(r0 + i) * FEAT + cg];
    ca1s[i] = 0.0f;
  }
  const float biasv = ca1bias[cg];
  const float wa0 = wca1act[cg * 2 + 0];
  const float wa1 = wca1act[cg * 2 + 1];

  // ---- publish initial ec3 (version 1) into parity buffer 0 ----
#pragma unroll
  for (int i = 0; i < 4; ++i)
    ec3buf[(r0 + i) * FEAT + cg] = f2bf(ec3s[i]);
  __syncthreads();
  const int fbase = bi * 32;
  if (tid == 0) {
    __builtin_amdgcn_fence(__ATOMIC_RELEASE, "agent");
    __hip_atomic_store(&ec3flag[fbase + nj], 1, __ATOMIC_RELAXED, __HIP_MEMORY_SCOPE_AGENT);
  }

  // ---- wait for drive, stage to LDS ----
  if (tid == 0) {
    while (__hip_atomic_load(&drvflag[nj], __ATOMIC_RELAXED, __HIP_MEMORY_SCOPE_AGENT) < 8)
      __builtin_amdgcn_s_sleep(1);
    __builtin_amdgcn_fence(__ATOMIC_ACQUIRE, "agent");
  }
  __syncthreads();
  for (int i = tid; i < NSTEP * 32; i += 256)
    drv[i] = driveg[(i >> 5) * FEAT + C + (i & 31)];
  __syncthreads();

  const short* b1p = w1l + (16 * fc + lc) * WPAD + kq;   // B: n=lane&15, k=8q+j
  const short* b2p = w2l + (16 * fc + lc) * WPAD + kq;

  // =================== main recurrence ===================
  for (int t = 0; t < NSTEP; ++t) {
    // ---- phase 1: ca1 = relu(drive*(1+sig(ec3@w1)) - bias) ----
    if (tid < 32) {
      const int* f = &ec3flag[fbase + tid];
      while (__hip_atomic_load(f, __ATOMIC_RELAXED, __HIP_MEMORY_SCOPE_AGENT) < t + 1)
        __builtin_amdgcn_s_sleep(1);
      __builtin_amdgcn_fence(__ATOMIC_ACQUIRE, "agent");
    }
    __syncthreads();

    {
      const short* eb = ec3buf + (t & 1) * (BSZ * FEAT) + rA * FEAT + kq;
      floatx4 acc0 = 0.0f, acc1 = 0.0f;
#pragma unroll
      for (int k = 0; k < FEAT; k += 64) {
        short8 a0 = *(const short8*)(eb + k);
        short8 a1 = *(const short8*)(eb + k + 32);
        short8 b0 = *(const short8*)(b1p + k);
        short8 b1 = *(const short8*)(b1p + k + 32);
        acc0 = mfma16(a0, b0, acc0);
        acc1 = mfma16(a1, b1, acc1);
      }
      const float drvv = drv[t * 32 + 16 * fc + lc];
#pragma unroll
      for (int i = 0; i < 4; ++i) {
        float dot = acc0[i] + acc1[i];
        float v = drvv * (1.0f + sigm(dot)) - biasv;
        ca1s[i] = fmaxf(v, 0.0f);
      }
      short* cb = ca1buf + (t & 1) * (BSZ * FEAT);
#pragma unroll
      for (int i = 0; i < 4; ++i)
        cb[(r0 + i) * FEAT + cg] = f2bf(ca1s[i]);
      if (r0 == 0) out[O_CAH + t * FEAT + cg] = ca1s[0];
    }
    __syncthreads();
    if (tid == 0) {
      __builtin_amdgcn_fence(__ATOMIC_RELEASE, "agent");
      __hip_atomic_store(&ca1flag[fbase + nj], t + 1, __ATOMIC_RELAXED, __HIP_MEMORY_SCOPE_AGENT);
    }

    // ---- phase 2: ec5 += ca1@w2 ; squash ; ec3 = ec5*ec3 ; cue mask ----
    if (tid < 32) {
      const int* f = &ca1flag[fbase + tid];
      while (__hip_atomic_load(f, __ATOMIC_RELAXED, __HIP_MEMORY_SCOPE_AGENT) < t + 1)
        __builtin_amdgcn_s_sleep(1);
      __builtin_amdgcn_fence(__ATOMIC_ACQUIRE, "agent");
    }
    __syncthreads();

    {
      const short* cbr = ca1buf + (t & 1) * (BSZ * FEAT) + rA * FEAT + kq;
      floatx4 acc0 = 0.0f, acc1 = 0.0f;
#pragma unroll
      for (int k = 0; k < FEAT; k += 64) {
        short8 a0 = *(const short8*)(cbr + k);
        short8 a1 = *(const short8*)(cbr + k + 32);
        short8 b0 = *(const short8*)(b2p + k);
        short8 b1 = *(const short8*)(b2p + k + 32);
        acc0 = mfma16(a0, b0, acc0);
        acc1 = mfma16(a1, b1, acc1);
      }
#pragma unroll
      for (int i = 0; i < 4; ++i) {
        float e5 = ec5s[i] + (acc0[i] + acc1[i]);          // 10*TS = 1.0
        e5 = 0.69f + 0.3f * sigm(4.0f * (e5 - 0.3f));
        ec5s[i] = e5;
        ec3s[i] = e5 * ec3s[i];
      }
      if (t == 16 || t == 24) {
        const int s = (t == 24) ? 1 : 0;
#pragma unroll
        for (int i = 0; i < 4; ++i) {
          int m = cue[(r0 + i) * 2048 + s * 1024 + cg];
          if (m) ec3s[i] = 0.4f * ec3s[i] + 0.6f;
        }
      }
      if (r0 == 0) {
        out[O_E3H + t * FEAT + cg] = ec3s[0];
        out[O_E5H + t * FEAT + cg] = ec5s[0];
      }
      if (t < NSTEP - 1) {
        short* ebw = ec3buf + ((t + 1) & 1) * (BSZ * FEAT);
#pragma unroll
        for (int i = 0; i < 4; ++i)
          ebw[(r0 + i) * FEAT + cg] = f2bf(ec3s[i]);
      }
    }
    if (t < NSTEP - 1) {
      __syncthreads();
      if (tid == 0) {
        __builtin_amdgcn_fence(__ATOMIC_RELEASE, "agent");
        __hip_atomic_store(&ec3flag[fbase + nj], t + 2, __ATOMIC_RELAXED, __HIP_MEMORY_SCOPE_AGENT);
      }
    }
  }

  // ---- final outputs ----
#pragma unroll
  for (int i = 0; i < 4; ++i) {
    out[O_E3 + (r0 + i) * FEAT + cg] = ec3s[i];
    out[O_E5 + (r0 + i) * FEAT + cg] = ec5s[i];
    out[O_CA + (r0 + i) * FEAT + cg] = ca1s[i];
    atomicAdd(&actred[(16 * fr + 4 * q + i) * 2 + 0], ca1s[i] * wa0);
    atomicAdd(&actred[(16 * fr + 4 * q + i) * 2 + 1], ca1s[i] * wa1);
  }
  __syncthreads();
  if (tid < 64) {
    float v = actred[tid];
    if (nj == 0) v += actbias[tid & 1];
    atomicAdd(&out[O_ACT + (R + (tid >> 1)) * 2 + (tid & 1)], v);
  }
}

extern "C" void kernel_launch(void* const* d_in, const int* in_sizes, int n_in,
                              void* d_out, int out_size, void* d_ws, size_t ws_size,
                              hipStream_t stream) {
  (void)in_sizes; (void)n_in; (void)out_size;
  if (ws_size < WS_NEED) return;  // visible failure rather than OOB

  const int*   cue      = (const int*)  d_in[0];
  const float* ec3_last = (const float*)d_in[1];
  const float* ec5_last = (const float*)d_in[2];
  // d_in[3] = ca1_last: dead in the reference (overwritten before use)
  const float* ca1bias  = (const float*)d_in[4];
  const float* wca3ca1  = (const float*)d_in[5];
  const float* wec3ca1  = (const float*)d_in[6];
  const float* wca1ec5  = (const float*)d_in[7];
  const float* wca1act  = (const float*)d_in[8];
  const float* actbias  = (const float*)d_in[9];

  char* ws = (char*)d_ws;
  // flags must start at 0 (ws is poisoned 0xAA before every launch)
  hipMemsetAsync(ws + OFF_EC3F, 0, 3 * 4096, stream);
  // actCell accumulated via atomicAdd
  hipMemsetAsync(d_out, 0, 512 * sizeof(float), stream);

  hipFuncSetAttribute(reinterpret_cast<const void*>(hpcrnn_kernel),
                      hipFuncAttributeMaxDynamicSharedMemorySize, LDS_TOTAL);

  hipLaunchKernelGGL(hpcrnn_kernel, dim3(256), dim3(256), LDS_TOTAL, stream,
                     cue, ec3_last, ec5_last, ca1bias, wca3ca1, wec3ca1,
                     wca1ec5, wca1act, actbias, (float*)d_out, ws);
}

// Round 2
// 1003.523 us; speedup vs baseline: 2.5549x; 2.5549x over previous
//
#include <hip/hip_runtime.h>
#include <stdint.h>

// ---------------- problem constants ----------------
#define NSTEP 100
#define BSZ   256
#define FEAT  1024
#define WPAD  1032   // padded K stride (bf16 elems) for LDS weight tiles

typedef __attribute__((ext_vector_type(8)))  short short8;
typedef __attribute__((ext_vector_type(4)))  float fx4;
typedef __attribute__((ext_vector_type(16))) float fx16;
typedef __attribute__((ext_vector_type(2)))  unsigned int u32x2;
typedef __attribute__((ext_vector_type(4)))  int i32x4;

// ---------------- workspace layout (bytes) ----------------
#define OFF_EC3   0u                         // 2*256*1024*2 = 1 MB (parity dbuf, bf16)
#define OFF_CA1   (1u << 20)                 // 1 MB
#define OFF_DRIVE (2u << 20)                 // 100*1024*4 = 400 KB
#define OFF_EC3F  (OFF_DRIVE + (512u << 10))
#define OFF_CA1F  (OFF_EC3F + 4096u)
#define OFF_DRVF  (OFF_CA1F + 4096u)
#define WS_NEED   (OFF_DRVF + 4096u)

// ---------------- output layout (float elems) ----------------
#define O_ACT 0
#define O_E3H 512
#define O_E5H (512 + 102400)
#define O_CAH (512 + 204800)
#define O_E3  (512 + 307200)
#define O_E5  (O_E3 + 262144)
#define O_CA  (O_E5 + 262144)

// ---------------- LDS layout (bytes) ----------------
// w1 [32][WPAD] bf16 (66048) | w2 (66048) | red4 [4][1024] f32 (16384)
#define LDS_W1    0
#define LDS_W2    66048
#define LDS_RED4  132096
#define LDS_TOTAL 148480   // <= 163840

__device__ __forceinline__ unsigned short f2bf(float x) {
  uint32_t u = __builtin_bit_cast(uint32_t, x);
  uint32_t r = (u + 0x7FFFu + ((u >> 16) & 1u)) >> 16;   // RNE
  return (unsigned short)r;
}
__device__ __forceinline__ float sigm(float x) { return 1.0f / (1.0f + __expf(-x)); }

// ---- per-access coherent (LLC / agent scope) memory ops: no cache flushes ----
__device__ __forceinline__ void llc_store_f32(float* p, float v) {
  asm volatile("global_store_dword %0, %1, off sc0 sc1" :: "v"(p), "v"(v) : "memory");
}
__device__ __forceinline__ void llc_store_b64(void* p, u32x2 v) {
  asm volatile("global_store_dwordx2 %0, %1, off sc0 sc1" :: "v"(p), "v"(v) : "memory");
}
#define VM_DRAIN() asm volatile("s_waitcnt vmcnt(0)" ::: "memory")
#define PIN(x)     asm volatile("" : "+v"(x))

__device__ __forceinline__ u32x2 packbf4(fx4 v) {
  u32x2 r;
  r[0] = (uint32_t)f2bf(v[0]) | ((uint32_t)f2bf(v[1]) << 16);
  r[1] = (uint32_t)f2bf(v[2]) | ((uint32_t)f2bf(v[3]) << 16);
  return r;
}

// One GEMM phase: out32x32(R-rows, C-cols) partials, wave w handles K-slice
// [w*256, w*256+256). A read coherently from global (sc0 sc1), B from LDS,
// partials to red4[w][row*32+col] (C-layout: col=lane&31, row=(reg&3)+8*(reg>>2)+4*(lane>>5)).
__device__ __forceinline__ void gemm_phase(const short* __restrict__ abuf,
                                           const short* __restrict__ wl,
                                           float* __restrict__ red4,
                                           int R, int tid) {
  const int lane = tid & 63, w = tid >> 6;
  const int m = lane & 31, h = lane >> 5;
  const short* ap = abuf + (size_t)(R + m) * FEAT + w * 256 + h * 8;
  const short* bp = wl + m * WPAD + w * 256 + h * 8;
  short8 A[16];
#pragma unroll
  for (int i = 0; i < 16; ++i)
    asm volatile("global_load_dwordx4 %0, %1, off sc0 sc1"
                 : "=v"(A[i]) : "v"(ap + i * 16) : "memory");
  asm volatile("s_waitcnt vmcnt(0)"
               : "+v"(A[0]), "+v"(A[1]), "+v"(A[2]), "+v"(A[3]),
                 "+v"(A[4]), "+v"(A[5]), "+v"(A[6]), "+v"(A[7]),
                 "+v"(A[8]), "+v"(A[9]), "+v"(A[10]), "+v"(A[11]),
                 "+v"(A[12]), "+v"(A[13]), "+v"(A[14]), "+v"(A[15])
               :: "memory");
  fx16 acc = 0.0f;
#pragma unroll
  for (int i = 0; i < 16; ++i) {
    short8 b = *(const short8*)(bp + i * 16);
    acc = __builtin_amdgcn_mfma_f32_32x32x16_bf16(A[i], b, acc, 0, 0, 0);
  }
#pragma unroll
  for (int i = 0; i < 16; ++i)
    red4[w * 1024 + ((i & 3) + 8 * (i >> 2) + 4 * h) * 32 + m] = acc[i];
}

extern "C" __global__ void __launch_bounds__(256)
hpcrnn_kernel(const int* __restrict__ cue,
              const float* __restrict__ ec3_last,
              const float* __restrict__ ec5_last,
              const float* __restrict__ ca1bias,
              const float* __restrict__ wca3ca1,
              const float* __restrict__ wec3ca1,
              const float* __restrict__ wca1ec5,
              const float* __restrict__ wca1act,
              const float* __restrict__ actbias,
              float* __restrict__ out,
              char* __restrict__ ws)
{
  extern __shared__ __attribute__((aligned(16))) char lds[];
  short* w1l  = (short*)(lds + LDS_W1);
  short* w2l  = (short*)(lds + LDS_W2);
  float* red4 = (float*)(lds + LDS_RED4);  // also reused as drive-red / actred

  const int tid = threadIdx.x;
  const int bi  = blockIdx.x & 7;    // batch group (32 rows)
  const int nj  = blockIdx.x >> 3;   // N chunk (32 cols)
  const int R   = bi * 32, C = nj * 32;

  short* ec3buf = (short*)(ws + OFF_EC3);
  short* ca1buf = (short*)(ws + OFF_CA1);
  float* driveg = (float*)(ws + OFF_DRIVE);
  int*   ec3flag = (int*)(ws + OFF_EC3F);
  int*   ca1flag = (int*)(ws + OFF_CA1F);
  int*   drvflag = (int*)(ws + OFF_DRVF);
  const int fbase = bi * 32;

  // ---- weights -> LDS, bf16, transposed to [n_local][k] ----
  {
    const int c = tid & 31;
    for (int k = tid >> 5; k < FEAT; k += 8) {
      w1l[c * WPAD + k] = (short)f2bf(wec3ca1[k * FEAT + C + c]);
      w2l[c * WPAD + k] = (short)f2bf(wca1ec5[k * FEAT + C + c]);
    }
  }

  // ---- per-thread element mapping: 1 row x 4 consecutive cols ----
  const int r  = tid >> 3;            // 0..31
  const int c0 = (tid & 7) * 4;       // 0,4,..,28
  const int rg = R + r;               // global row
  const int cg = C + c0;              // global col base

  const fx4 biasv  = *(const fx4*)(ca1bias + cg);
  const fx4 wact01 = *(const fx4*)(wca1act + cg * 2);       // cols c0,c0+1 x {a0,a1}
  const fx4 wact23 = *(const fx4*)(wca1act + cg * 2 + 4);
  fx4 ec3v = *(const fx4*)(ec3_last + (size_t)rg * FEAT + cg);
  fx4 ec5v = *(const fx4*)(ec5_last + (size_t)rg * FEAT + cg);
  fx4 ca1v = 0.0f;

  // ---- publish initial ec3 (version 1 -> parity 0) ----
  llc_store_b64(ec3buf + (size_t)rg * FEAT + cg, packbf4(ec3v));
  VM_DRAIN();
  __syncthreads();
  if (tid == 0)
    __hip_atomic_store(&ec3flag[fbase + nj], 1, __ATOMIC_RELAXED, __HIP_MEMORY_SCOPE_AGENT);

  // ---- drive precompute: this block does t === bi (mod 8), cols C..C+31 ----
  {
    float* dred = red4;               // [8][32] scratch
    const int g = tid >> 5, n = tid & 31;
    for (int t = bi; t < NSTEP; t += 8) {
      float part = 0.0f;
      const float tf = (float)t;
      for (int c = g * 128; c < g * 128 + 128; ++c) {
        float d = (float)c * (100.0f / 1023.0f) - tf;
        part += __expf(d * d * -0.02f) * wca3ca1[c * FEAT + C + n];
      }
      __syncthreads();
      dred[g * 32 + n] = part;
      __syncthreads();
      if (g == 0) {
        float s = 0.0f;
#pragma unroll
        for (int gg = 0; gg < 8; ++gg) s += dred[gg * 32 + n];
        llc_store_f32(driveg + t * FEAT + C + n, s);
      }
    }
    VM_DRAIN();
    __syncthreads();
    if (tid == 0)
      __hip_atomic_fetch_add(&drvflag[nj], 1, __ATOMIC_RELAXED, __HIP_MEMORY_SCOPE_AGENT);
    if (tid == 0) {
      while (__hip_atomic_load(&drvflag[nj], __ATOMIC_RELAXED, __HIP_MEMORY_SCOPE_AGENT) < 8)
        __builtin_amdgcn_s_sleep(1);
    }
    __syncthreads();
  }

  // =================== main recurrence ===================
  for (int t = 0; t < NSTEP; ++t) {
    const size_t par = (size_t)(t & 1) * (BSZ * FEAT);

    // ---- phase 1: ca1 = relu(drive*(1+sig(ec3@w1)) - bias) ----
    if (tid < 32) {
      const int* f = &ec3flag[fbase + tid];
      while (__hip_atomic_load(f, __ATOMIC_RELAXED, __HIP_MEMORY_SCOPE_AGENT) < t + 1)
        __builtin_amdgcn_s_sleep(1);
    }
    __syncthreads();

    fx4 dv;
    asm volatile("global_load_dwordx4 %0, %1, off sc0 sc1"
                 : "=v"(dv) : "v"(driveg + t * FEAT + cg) : "memory");
    gemm_phase(ec3buf + par, w1l, red4, R, tid);   // internal vmcnt(0) also drains dv
    PIN(dv);
    __syncthreads();

    {
      const int e0 = 4 * tid;
      fx4 p0 = *(const fx4*)(red4 + e0);
      fx4 p1 = *(const fx4*)(red4 + 1024 + e0);
      fx4 p2 = *(const fx4*)(red4 + 2048 + e0);
      fx4 p3 = *(const fx4*)(red4 + 3072 + e0);
#pragma unroll
      for (int j = 0; j < 4; ++j) {
        float dot = (p0[j] + p1[j]) + (p2[j] + p3[j]);
        float v = dv[j] * (1.0f + sigm(dot)) - biasv[j];
        ca1v[j] = fmaxf(v, 0.0f);
      }
      llc_store_b64(ca1buf + par + (size_t)rg * FEAT + cg, packbf4(ca1v));
      if (rg == 0) *(fx4*)(out + O_CAH + t * FEAT + cg) = ca1v;
    }
    VM_DRAIN();
    __syncthreads();
    if (tid == 0)
      __hip_atomic_store(&ca1flag[fbase + nj], t + 1, __ATOMIC_RELAXED, __HIP_MEMORY_SCOPE_AGENT);

    // ---- phase 2: ec5 += ca1@w2 ; squash ; ec3 = ec5*ec3 ; cue mask ----
    if (tid < 32) {
      const int* f = &ca1flag[fbase + tid];
      while (__hip_atomic_load(f, __ATOMIC_RELAXED, __HIP_MEMORY_SCOPE_AGENT) < t + 1)
        __builtin_amdgcn_s_sleep(1);
    }
    __syncthreads();

    gemm_phase(ca1buf + par, w2l, red4, R, tid);
    __syncthreads();

    {
      const int e0 = 4 * tid;
      fx4 p0 = *(const fx4*)(red4 + e0);
      fx4 p1 = *(const fx4*)(red4 + 1024 + e0);
      fx4 p2 = *(const fx4*)(red4 + 2048 + e0);
      fx4 p3 = *(const fx4*)(red4 + 3072 + e0);
#pragma unroll
      for (int j = 0; j < 4; ++j) {
        float e5 = ec5v[j] + ((p0[j] + p1[j]) + (p2[j] + p3[j]));  // 10*TS = 1.0
        e5 = 0.69f + 0.3f * sigm(4.0f * (e5 - 0.3f));
        ec5v[j] = e5;
        ec3v[j] = e5 * ec3v[j];
      }
      if (t == 16 || t == 24) {
        const int s = (t == 24) ? 1 : 0;
        i32x4 m = *(const i32x4*)(cue + (size_t)rg * 2048 + s * 1024 + cg);
#pragma unroll
        for (int j = 0; j < 4; ++j)
          if (m[j]) ec3v[j] = 0.4f * ec3v[j] + 0.6f;
      }
      if (rg == 0) {
        *(fx4*)(out + O_E3H + t * FEAT + cg) = ec3v;
        *(fx4*)(out + O_E5H + t * FEAT + cg) = ec5v;
      }
      if (t < NSTEP - 1) {
        const size_t parn = (size_t)((t + 1) & 1) * (BSZ * FEAT);
        llc_store_b64(ec3buf + parn + (size_t)rg * FEAT + cg, packbf4(ec3v));
      }
    }
    VM_DRAIN();
    __syncthreads();
    if (tid == 0 && t < NSTEP - 1)
      __hip_atomic_store(&ec3flag[fbase + nj], t + 2, __ATOMIC_RELAXED, __HIP_MEMORY_SCOPE_AGENT);
  }

  // ---- epilogue: finals + actCell ----
  float* ared = red4;   // [32][2], reuse
  __syncthreads();
  if (tid < 64) ared[tid] = 0.0f;
  __syncthreads();
  {
    float p0 = ca1v[0] * wact01[0] + ca1v[1] * wact01[2] +
               ca1v[2] * wact23[0] + ca1v[3] * wact23[2];
    float p1 = ca1v[0] * wact01[1] + ca1v[1] * wact01[3] +
               ca1v[2] * wact23[1] + ca1v[3] * wact23[3];
    atomicAdd(&ared[r * 2 + 0], p0);
    atomicAdd(&ared[r * 2 + 1], p1);
  }
  *(fx4*)(out + O_E3 + (size_t)rg * FEAT + cg) = ec3v;
  *(fx4*)(out + O_E5 + (size_t)rg * FEAT + cg) = ec5v;
  *(fx4*)(out + O_CA + (size_t)rg * FEAT + cg) = ca1v;
  __syncthreads();
  if (tid < 64) {
    float v = ared[tid];
    if (nj == 0) v += actbias[tid & 1];
    atomicAdd(&out[O_ACT + (R + (tid >> 1)) * 2 + (tid & 1)], v);
  }
}

extern "C" void kernel_launch(void* const* d_in, const int* in_sizes, int n_in,
                              void* d_out, int out_size, void* d_ws, size_t ws_size,
                              hipStream_t stream) {
  (void)in_sizes; (void)n_in; (void)out_size;
  if (ws_size < WS_NEED) return;

  const int*   cue      = (const int*)  d_in[0];
  const float* ec3_last = (const float*)d_in[1];
  const float* ec5_last = (const float*)d_in[2];
  // d_in[3] = ca1_last: dead in the reference (overwritten before use)
  const float* ca1bias  = (const float*)d_in[4];
  const float* wca3ca1  = (const float*)d_in[5];
  const float* wec3ca1  = (const float*)d_in[6];
  const float* wca1ec5  = (const float*)d_in[7];
  const float* wca1act  = (const float*)d_in[8];
  const float* actbias  = (const float*)d_in[9];

  char* ws = (char*)d_ws;
  hipMemsetAsync(ws + OFF_EC3F, 0, 3 * 4096, stream);   // flags start at 0
  hipMemsetAsync(d_out, 0, 512 * sizeof(float), stream);

  hipFuncSetAttribute(reinterpret_cast<const void*>(hpcrnn_kernel),
                      hipFuncAttributeMaxDynamicSharedMemorySize, LDS_TOTAL);

  hipLaunchKernelGGL(hpcrnn_kernel, dim3(256), dim3(256), LDS_TOTAL, stream,
                     cue, ec3_last, ec5_last, ca1bias, wca3ca1, wec3ca1,
                     wca1ec5, wca1act, actbias, (float*)d_out, ws);
}

// Round 3
// 788.120 us; speedup vs baseline: 3.2532x; 1.2733x over previous
//
#include <hip/hip_runtime.h>
#include <stdint.h>

// ---------------- problem constants ----------------
#define NSTEP 100
#define BSZ   256
#define FEAT  1024
#define WPAD  1032   // padded K stride (bf16 elems) for LDS weight tiles

typedef __attribute__((ext_vector_type(8)))  short short8;
typedef __attribute__((ext_vector_type(4)))  float fx4;
typedef __attribute__((ext_vector_type(16))) float fx16;
typedef __attribute__((ext_vector_type(2)))  unsigned int u32x2;
typedef __attribute__((ext_vector_type(4)))  int i32x4;

// ---------------- workspace layout (bytes) ----------------
// Activation buffers: parity-double-buffered, 8 groups x (32 rows x 1024 cols) bf16.
// Within a group, element (local row m, col c) lives at short index
//   ((c>>3)*32 + m)*8 + (c&7)
// so a consumer wave's A-fragment loads are fully contiguous (see gemm_phase).
#define OFF_EC3   0u                         // 2 * 8 * 32768 shorts = 1 MB
#define OFF_CA1   (1u << 20)                 // 1 MB
#define OFF_DRIVE (2u << 20)                 // 100*1024*4 = 400 KB
#define OFF_EC3F  (OFF_DRIVE + (512u << 10))
#define OFF_CA1F  (OFF_EC3F + 4096u)
#define OFF_DRVF  (OFF_CA1F + 4096u)
#define WS_NEED   (OFF_DRVF + 4096u)

#define GSTRIDE 32768                        // shorts per group (32*1024)
#define PSTRIDE (8 * GSTRIDE)                // shorts per parity buffer

// ---------------- output layout (float elems) ----------------
#define O_ACT 0
#define O_E3H 512
#define O_E5H (512 + 102400)
#define O_CAH (512 + 204800)
#define O_E3  (512 + 307200)
#define O_E5  (O_E3 + 262144)
#define O_CA  (O_E5 + 262144)

// ---------------- LDS layout (bytes) ----------------
// w1 [32][WPAD] bf16 (66048) | w2 (66048) | red4 [4][1024] f32 (16384) | drv [100][32] f32 (12800)
#define LDS_W1    0
#define LDS_W2    66048
#define LDS_RED4  132096
#define LDS_DRV   148480
#define LDS_TOTAL 161280   // <= 163840

__device__ __forceinline__ unsigned short f2bf(float x) {
  uint32_t u = __builtin_bit_cast(uint32_t, x);
  uint32_t r = (u + 0x7FFFu + ((u >> 16) & 1u)) >> 16;   // RNE
  return (unsigned short)r;
}
__device__ __forceinline__ float sigm(float x) { return 1.0f / (1.0f + __expf(-x)); }

// ---- per-access coherent (LLC / agent scope) memory ops: no cache flushes ----
__device__ __forceinline__ void llc_store_f32(float* p, float v) {
  asm volatile("global_store_dword %0, %1, off sc0 sc1" :: "v"(p), "v"(v) : "memory");
}
__device__ __forceinline__ void llc_store_b64(void* p, u32x2 v) {
  asm volatile("global_store_dwordx2 %0, %1, off sc0 sc1" :: "v"(p), "v"(v) : "memory");
}
#define VM_DRAIN() asm volatile("s_waitcnt vmcnt(0)" ::: "memory")

__device__ __forceinline__ u32x2 packbf4(fx4 v) {
  u32x2 r;
  r[0] = (uint32_t)f2bf(v[0]) | ((uint32_t)f2bf(v[1]) << 16);
  r[1] = (uint32_t)f2bf(v[2]) | ((uint32_t)f2bf(v[3]) << 16);
  return r;
}

// One GEMM phase: 32x32 out tile partials; wave w handles K-slice [256w,256w+256).
// A read coherently (sc0 sc1) from the chunked group buffer: for MFMA step i the
// lane (m=lane&31, h=lane>>5) needs chunk (32w + 2i + h), row m -> short offset
// (32w+h)*256 + m*8 + i*512. Lanes are consecutive 16B chunks => 1KB contiguous
// per load instruction. B from LDS. Partials to red4[w][row*32+col]
// (C-layout: col=lane&31, row=(reg&3)+8*(reg>>2)+4*(lane>>5)).
__device__ __forceinline__ void gemm_phase(const short* __restrict__ abuf,
                                           const short* __restrict__ wl,
                                           float* __restrict__ red4, int tid) {
  const int lane = tid & 63, w = tid >> 6;
  const int m = lane & 31, h = lane >> 5;
  const short* ap = abuf + (32 * w + h) * 256 + m * 8;
  const short* bp = wl + m * WPAD + w * 256 + h * 8;
  short8 A[16];
#pragma unroll
  for (int i = 0; i < 16; ++i)
    asm volatile("global_load_dwordx4 %0, %1, off sc0 sc1"
                 : "=v"(A[i]) : "v"(ap + i * 512) : "memory");
  asm volatile("s_waitcnt vmcnt(0)"
               : "+v"(A[0]), "+v"(A[1]), "+v"(A[2]), "+v"(A[3]),
                 "+v"(A[4]), "+v"(A[5]), "+v"(A[6]), "+v"(A[7]),
                 "+v"(A[8]), "+v"(A[9]), "+v"(A[10]), "+v"(A[11]),
                 "+v"(A[12]), "+v"(A[13]), "+v"(A[14]), "+v"(A[15])
               :: "memory");
  fx16 acc = 0.0f;
#pragma unroll
  for (int i = 0; i < 16; ++i) {
    short8 b = *(const short8*)(bp + i * 16);
    acc = __builtin_amdgcn_mfma_f32_32x32x16_bf16(A[i], b, acc, 0, 0, 0);
  }
#pragma unroll
  for (int i = 0; i < 16; ++i)
    red4[w * 1024 + ((i & 3) + 8 * (i >> 2) + 4 * h) * 32 + m] = acc[i];
}

extern "C" __global__ void __launch_bounds__(256)
hpcrnn_kernel(const int* __restrict__ cue,
              const float* __restrict__ ec3_last,
              const float* __restrict__ ec5_last,
              const float* __restrict__ ca1bias,
              const float* __restrict__ wca3ca1,
              const float* __restrict__ wec3ca1,
              const float* __restrict__ wca1ec5,
              const float* __restrict__ wca1act,
              const float* __restrict__ actbias,
              float* __restrict__ out,
              char* __restrict__ ws)
{
  extern __shared__ __attribute__((aligned(16))) char lds[];
  short* w1l  = (short*)(lds + LDS_W1);
  short* w2l  = (short*)(lds + LDS_W2);
  float* red4 = (float*)(lds + LDS_RED4);  // also reused as drive-red / actred
  float* drvl = (float*)(lds + LDS_DRV);   // [100][32]

  const int tid = threadIdx.x;
  const int bi  = blockIdx.x & 7;    // batch group (32 rows)
  const int nj  = blockIdx.x >> 3;   // N chunk (32 cols)
  const int R   = bi * 32, C = nj * 32;

  short* ec3buf = (short*)(ws + OFF_EC3);
  short* ca1buf = (short*)(ws + OFF_CA1);
  float* driveg = (float*)(ws + OFF_DRIVE);
  int*   ec3flag = (int*)(ws + OFF_EC3F);
  int*   ca1flag = (int*)(ws + OFF_CA1F);
  int*   drvflag = (int*)(ws + OFF_DRVF);
  const int fbase = bi * 32;

  // ---- weights -> LDS, bf16, transposed to [n_local][k] ----
  {
    const int c = tid & 31;
    for (int k = tid >> 5; k < FEAT; k += 8) {
      w1l[c * WPAD + k] = (short)f2bf(wec3ca1[k * FEAT + C + c]);
      w2l[c * WPAD + k] = (short)f2bf(wca1ec5[k * FEAT + C + c]);
    }
  }

  // ---- per-thread element mapping: 1 row x 4 consecutive cols ----
  const int r  = tid >> 3;            // local row 0..31
  const int c0 = (tid & 7) * 4;       // local col base 0,4,..,28
  const int rg = R + r;               // global row
  const int cg = C + c0;              // global col base
  // chunked store offset inside this group's buffer (shorts):
  const size_t stoff = (size_t)(((cg >> 3) * 32 + r) * 8 + (c0 & 7));
  const size_t gbase = (size_t)bi * GSTRIDE;

  const fx4 biasv  = *(const fx4*)(ca1bias + cg);
  const fx4 wact01 = *(const fx4*)(wca1act + cg * 2);
  const fx4 wact23 = *(const fx4*)(wca1act + cg * 2 + 4);
  fx4 ec3v = *(const fx4*)(ec3_last + (size_t)rg * FEAT + cg);
  fx4 ec5v = *(const fx4*)(ec5_last + (size_t)rg * FEAT + cg);
  fx4 ca1v = 0.0f;

  // ---- publish initial ec3 (version 1 -> parity 0) ----
  llc_store_b64(ec3buf + gbase + stoff, packbf4(ec3v));
  VM_DRAIN();
  __syncthreads();
  if (tid == 0)
    __hip_atomic_store(&ec3flag[fbase + nj], 1, __ATOMIC_RELAXED, __HIP_MEMORY_SCOPE_AGENT);

  // ---- drive precompute: this block does t === bi (mod 8), cols C..C+31 ----
  {
    float* dred = red4;               // [8][32] scratch
    const int g = tid >> 5, n = tid & 31;
    for (int t = bi; t < NSTEP; t += 8) {
      float part = 0.0f;
      const float tf = (float)t;
      for (int c = g * 128; c < g * 128 + 128; ++c) {
        float d = (float)c * (100.0f / 1023.0f) - tf;
        part += __expf(d * d * -0.02f) * wca3ca1[c * FEAT + C + n];
      }
      __syncthreads();
      dred[g * 32 + n] = part;
      __syncthreads();
      if (g == 0) {
        float s = 0.0f;
#pragma unroll
        for (int gg = 0; gg < 8; ++gg) s += dred[gg * 32 + n];
        llc_store_f32(driveg + t * FEAT + C + n, s);
      }
    }
    VM_DRAIN();
    __syncthreads();
    if (tid == 0) {
      __hip_atomic_fetch_add(&drvflag[nj], 1, __ATOMIC_RELAXED, __HIP_MEMORY_SCOPE_AGENT);
      while (__hip_atomic_load(&drvflag[nj], __ATOMIC_RELAXED, __HIP_MEMORY_SCOPE_AGENT) < 8)
        __builtin_amdgcn_s_sleep(1);
    }
    __syncthreads();
    // stage this block's drive columns into LDS
    for (int i = tid; i < NSTEP * 32; i += 256) {
      float v;
      asm volatile("global_load_dword %0, %1, off sc0 sc1"
                   : "=v"(v) : "v"(driveg + (i >> 5) * FEAT + C + (i & 31)) : "memory");
      asm volatile("s_waitcnt vmcnt(0)" : "+v"(v) :: "memory");
      drvl[i] = v;
    }
    __syncthreads();
  }

  // =================== main recurrence ===================
  const int lane = tid & 63, wv = tid >> 6;
  for (int t = 0; t < NSTEP; ++t) {
    const size_t par = (size_t)(t & 1) * PSTRIDE;

    // ---- phase 1: ca1 = relu(drive*(1+sig(ec3@w1)) - bias) ----
    // wave wv's K-slice depends only on producers nj in [8wv, 8wv+8)
    if (lane < 8) {
      const int* f = &ec3flag[fbase + 8 * wv + lane];
      while (__hip_atomic_load(f, __ATOMIC_RELAXED, __HIP_MEMORY_SCOPE_AGENT) < t + 1)
        __builtin_amdgcn_s_sleep(1);
    }
    gemm_phase(ec3buf + par + gbase, w1l, red4, tid);
    __syncthreads();                                  // barrier A: partials ready

    {
      const int e0 = 4 * tid;
      fx4 p0 = *(const fx4*)(red4 + e0);
      fx4 p1 = *(const fx4*)(red4 + 1024 + e0);
      fx4 p2 = *(const fx4*)(red4 + 2048 + e0);
      fx4 p3 = *(const fx4*)(red4 + 3072 + e0);
      const fx4 dv = *(const fx4*)(drvl + t * 32 + c0);
#pragma unroll
      for (int j = 0; j < 4; ++j) {
        float dot = (p0[j] + p1[j]) + (p2[j] + p3[j]);
        float v = dv[j] * (1.0f + sigm(dot)) - biasv[j];
        ca1v[j] = fmaxf(v, 0.0f);
      }
      llc_store_b64(ca1buf + par + gbase + stoff, packbf4(ca1v));
      if (rg == 0) *(fx4*)(out + O_CAH + t * FEAT + cg) = ca1v;
    }
    VM_DRAIN();
    __syncthreads();                                  // barrier B: all stores drained
    if (tid == 0)
      __hip_atomic_store(&ca1flag[fbase + nj], t + 1, __ATOMIC_RELAXED, __HIP_MEMORY_SCOPE_AGENT);

    // ---- phase 2: ec5 += ca1@w2 ; squash ; ec3 = ec5*ec3 ; cue mask ----
    if (lane < 8) {
      const int* f = &ca1flag[fbase + 8 * wv + lane];
      while (__hip_atomic_load(f, __ATOMIC_RELAXED, __HIP_MEMORY_SCOPE_AGENT) < t + 1)
        __builtin_amdgcn_s_sleep(1);
    }
    gemm_phase(ca1buf + par + gbase, w2l, red4, tid);
    __syncthreads();                                  // barrier A

    {
      const int e0 = 4 * tid;
      fx4 p0 = *(const fx4*)(red4 + e0);
      fx4 p1 = *(const fx4*)(red4 + 1024 + e0);
      fx4 p2 = *(const fx4*)(red4 + 2048 + e0);
      fx4 p3 = *(const fx4*)(red4 + 3072 + e0);
#pragma unroll
      for (int j = 0; j < 4; ++j) {
        float e5 = ec5v[j] + ((p0[j] + p1[j]) + (p2[j] + p3[j]));  // 10*TS = 1.0
        e5 = 0.69f + 0.3f * sigm(4.0f * (e5 - 0.3f));
        ec5v[j] = e5;
        ec3v[j] = e5 * ec3v[j];
      }
      if (t == 16 || t == 24) {
        const int s = (t == 24) ? 1 : 0;
        i32x4 m = *(const i32x4*)(cue + (size_t)rg * 2048 + s * 1024 + cg);
#pragma unroll
        for (int j = 0; j < 4; ++j)
          if (m[j]) ec3v[j] = 0.4f * ec3v[j] + 0.6f;
      }
      if (rg == 0) {
        *(fx4*)(out + O_E3H + t * FEAT + cg) = ec3v;
        *(fx4*)(out + O_E5H + t * FEAT + cg) = ec5v;
      }
      if (t < NSTEP - 1) {
        const size_t parn = (size_t)((t + 1) & 1) * PSTRIDE;
        llc_store_b64(ec3buf + parn + gbase + stoff, packbf4(ec3v));
      }
    }
    VM_DRAIN();
    __syncthreads();                                  // barrier B
    if (tid == 0 && t < NSTEP - 1)
      __hip_atomic_store(&ec3flag[fbase + nj], t + 2, __ATOMIC_RELAXED, __HIP_MEMORY_SCOPE_AGENT);
  }

  // ---- epilogue: finals + actCell ----
  float* ared = red4;   // [32][2], reuse
  __syncthreads();
  if (tid < 64) ared[tid] = 0.0f;
  __syncthreads();
  {
    float p0 = ca1v[0] * wact01[0] + ca1v[1] * wact01[2] +
               ca1v[2] * wact23[0] + ca1v[3] * wact23[2];
    float p1 = ca1v[0] * wact01[1] + ca1v[1] * wact01[3] +
               ca1v[2] * wact23[1] + ca1v[3] * wact23[3];
    atomicAdd(&ared[r * 2 + 0], p0);
    atomicAdd(&ared[r * 2 + 1], p1);
  }
  *(fx4*)(out + O_E3 + (size_t)rg * FEAT + cg) = ec3v;
  *(fx4*)(out + O_E5 + (size_t)rg * FEAT + cg) = ec5v;
  *(fx4*)(out + O_CA + (size_t)rg * FEAT + cg) = ca1v;
  __syncthreads();
  if (tid < 64) {
    float v = ared[tid];
    if (nj == 0) v += actbias[tid & 1];
    atomicAdd(&out[O_ACT + (R + (tid >> 1)) * 2 + (tid & 1)], v);
  }
}

extern "C" void kernel_launch(void* const* d_in, const int* in_sizes, int n_in,
                              void* d_out, int out_size, void* d_ws, size_t ws_size,
                              hipStream_t stream) {
  (void)in_sizes; (void)n_in; (void)out_size;
  if (ws_size < WS_NEED) return;

  const int*   cue      = (const int*)  d_in[0];
  const float* ec3_last = (const float*)d_in[1];
  const float* ec5_last = (const float*)d_in[2];
  // d_in[3] = ca1_last: dead in the reference (overwritten before use)
  const float* ca1bias  = (const float*)d_in[4];
  const float* wca3ca1  = (const float*)d_in[5];
  const float* wec3ca1  = (const float*)d_in[6];
  const float* wca1ec5  = (const float*)d_in[7];
  const float* wca1act  = (const float*)d_in[8];
  const float* actbias  = (const float*)d_in[9];

  char* ws = (char*)d_ws;
  hipMemsetAsync(ws + OFF_EC3F, 0, 3 * 4096, stream);   // flags start at 0
  hipMemsetAsync(d_out, 0, 512 * sizeof(float), stream);

  hipFuncSetAttribute(reinterpret_cast<const void*>(hpcrnn_kernel),
                      hipFuncAttributeMaxDynamicSharedMemorySize, LDS_TOTAL);

  hipLaunchKernelGGL(hpcrnn_kernel, dim3(256), dim3(256), LDS_TOTAL, stream,
                     cue, ec3_last, ec5_last, ca1bias, wca3ca1, wec3ca1,
                     wca1ec5, wca1act, actbias, (float*)d_out, ws);
}

// Round 5
// 763.342 us; speedup vs baseline: 3.3588x; 1.0325x over previous
//
#include <hip/hip_runtime.h>
#include <stdint.h>

// ---------------- problem constants ----------------
#define NSTEP 100
#define BSZ   256
#define FEAT  1024
#define WPAD  1032   // padded K stride (bf16 elems) for LDS weight tiles
#define SPIN_CAP (1 << 22)   // poll bound: converts protocol bugs into absmax fails

typedef __attribute__((ext_vector_type(8)))  short short8;
typedef __attribute__((ext_vector_type(4)))  float fx4;
typedef __attribute__((ext_vector_type(16))) float fx16;
typedef __attribute__((ext_vector_type(2)))  unsigned int u32x2;
typedef __attribute__((ext_vector_type(4)))  int i32x4;

// ---------------- workspace layout (bytes) ----------------
// Activation exchange: parity-double-buffered, 8 groups x (32 rows x 1024 cols) bf16.
// Data plane is XCD-L2-local (sc0) when the whole group shares an XCD (runtime
// verified via HW_REG_XCC_ID rendezvous); otherwise LLC-coherent (sc0 sc1).
// Control plane (flags) is ALWAYS agent-scope at the LLC (R3-proven).
// Within a group, element (local row m, col c) lives at short index
//   ((c>>3)*32 + m)*8 + (c&7)   (consumer A-loads fully contiguous).
#define OFF_EC3   0u
#define OFF_CA1   (1u << 20)
#define OFF_DRIVE (2u << 20)
#define OFF_EC3F  (OFF_DRIVE + (512u << 10))
#define OFF_CA1F  (OFF_EC3F + 4096u)
#define OFF_DRVF  (OFF_CA1F + 4096u)
#define OFF_GRP   (OFF_DRVF + 4096u)   // grpmask[8] @ +0, grpcnt[8] @ +512
#define WS_NEED   (OFF_GRP + 4096u)

#define GSTRIDE 32768                  // shorts per group (32*1024)
#define PSTRIDE (8 * GSTRIDE)          // shorts per parity buffer

// ---------------- output layout (float elems) ----------------
#define O_ACT 0
#define O_E3H 512
#define O_E5H (512 + 102400)
#define O_CAH (512 + 204800)
#define O_E3  (512 + 307200)
#define O_E5  (O_E3 + 262144)
#define O_CA  (O_E5 + 262144)

// ---------------- LDS layout (bytes) ----------------
#define LDS_W1    0
#define LDS_W2    66048
#define LDS_RED4  132096               // 4*1024 f32 = 16384
#define LDS_DRV   148480               // 100*32 f32 = 12800
#define LDS_UNI   161280               // 1 int
#define LDS_TOTAL 161296               // <= 163840

__device__ __forceinline__ unsigned short f2bf(float x) {
  uint32_t u = __builtin_bit_cast(uint32_t, x);
  uint32_t r = (u + 0x7FFFu + ((u >> 16) & 1u)) >> 16;   // RNE
  return (unsigned short)r;
}
__device__ __forceinline__ float sigm(float x) { return 1.0f / (1.0f + __expf(-x)); }

#define VM_DRAIN() asm volatile("s_waitcnt vmcnt(0)" ::: "memory")

// exchange store: uni -> dirty line in shared XCD L2; else -> LLC coherent
__device__ __forceinline__ void ex_store(void* p, u32x2 v, bool uni) {
  if (uni) asm volatile("global_store_dwordx2 %0, %1, off sc0"     :: "v"(p), "v"(v) : "memory");
  else     asm volatile("global_store_dwordx2 %0, %1, off sc0 sc1" :: "v"(p), "v"(v) : "memory");
}
__device__ __forceinline__ void llc_store_f32(float* p, float v) {
  asm volatile("global_store_dword %0, %1, off sc0 sc1" :: "v"(p), "v"(v) : "memory");
}
// control plane: agent scope, always
__device__ __forceinline__ void flag_add(int* p) {
  __hip_atomic_fetch_add(p, 1, __ATOMIC_RELAXED, __HIP_MEMORY_SCOPE_AGENT);
}
__device__ __forceinline__ int flag_peek(const int* p) {
  return __hip_atomic_load(p, __ATOMIC_RELAXED, __HIP_MEMORY_SCOPE_AGENT);
}
__device__ __forceinline__ void flag_wait(const int* p, int tgt) {
  int sp = 0;
  while (flag_peek(p) < tgt) {
    __builtin_amdgcn_s_sleep(1);
    if (++sp > SPIN_CAP) break;   // bounded: surface as absmax fail, not hang
  }
}

__device__ __forceinline__ u32x2 packbf4(fx4 v) {
  u32x2 r;
  r[0] = (uint32_t)f2bf(v[0]) | ((uint32_t)f2bf(v[1]) << 16);
  r[1] = (uint32_t)f2bf(v[2]) | ((uint32_t)f2bf(v[3]) << 16);
  return r;
}

// 32x32 out-tile partials; wave w handles K-slice [256w,256w+256).
// A from the chunked group buffer (contiguous 1KB per load inst), B from LDS.
// Partials to red4[w][row*32+col] (C: col=lane&31, row=(reg&3)+8*(reg>>2)+4*(lane>>5)).
template <bool UNI>
__device__ __forceinline__ void gemm_phase(const short* __restrict__ abuf,
                                           const short* __restrict__ wl,
                                           float* __restrict__ red4, int tid) {
  const int lane = tid & 63, w = tid >> 6;
  const int m = lane & 31, h = lane >> 5;
  const short* ap = abuf + (32 * w + h) * 256 + m * 8;
  const short* bp = wl + m * WPAD + w * 256 + h * 8;
  short8 A[16];
  if (UNI) {
#pragma unroll
    for (int i = 0; i < 16; ++i)
      asm volatile("global_load_dwordx4 %0, %1, off sc0"
                   : "=v"(A[i]) : "v"(ap + i * 512) : "memory");
  } else {
#pragma unroll
    for (int i = 0; i < 16; ++i)
      asm volatile("global_load_dwordx4 %0, %1, off sc0 sc1"
                   : "=v"(A[i]) : "v"(ap + i * 512) : "memory");
  }
  asm volatile("s_waitcnt vmcnt(0)"
               : "+v"(A[0]), "+v"(A[1]), "+v"(A[2]), "+v"(A[3]),
                 "+v"(A[4]), "+v"(A[5]), "+v"(A[6]), "+v"(A[7]),
                 "+v"(A[8]), "+v"(A[9]), "+v"(A[10]), "+v"(A[11]),
                 "+v"(A[12]), "+v"(A[13]), "+v"(A[14]), "+v"(A[15])
               :: "memory");
  fx16 acc = 0.0f;
#pragma unroll
  for (int i = 0; i < 16; ++i) {
    short8 b = *(const short8*)(bp + i * 16);
    acc = __builtin_amdgcn_mfma_f32_32x32x16_bf16(A[i], b, acc, 0, 0, 0);
  }
#pragma unroll
  for (int i = 0; i < 16; ++i)
    red4[w * 1024 + ((i & 3) + 8 * (i >> 2) + 4 * h) * 32 + m] = acc[i];
}

extern "C" __global__ void __launch_bounds__(256)
hpcrnn_kernel(const int* __restrict__ cue,
              const float* __restrict__ ec3_last,
              const float* __restrict__ ec5_last,
              const float* __restrict__ ca1bias,
              const float* __restrict__ wca3ca1,
              const float* __restrict__ wec3ca1,
              const float* __restrict__ wca1ec5,
              const float* __restrict__ wca1act,
              const float* __restrict__ actbias,
              float* __restrict__ out,
              char* __restrict__ ws)
{
  extern __shared__ __attribute__((aligned(16))) char lds[];
  short* w1l  = (short*)(lds + LDS_W1);
  short* w2l  = (short*)(lds + LDS_W2);
  float* red4 = (float*)(lds + LDS_RED4);
  float* drvl = (float*)(lds + LDS_DRV);
  int*   unil = (int*)(lds + LDS_UNI);

  const int tid = threadIdx.x;
  const int bi  = blockIdx.x & 7;    // batch group; %8 == XCD residue (round-robin heuristic)
  const int nj  = blockIdx.x >> 3;   // N chunk (32 cols)
  const int R   = bi * 32, C = nj * 32;

  short* ec3buf = (short*)(ws + OFF_EC3);
  short* ca1buf = (short*)(ws + OFF_CA1);
  float* driveg = (float*)(ws + OFF_DRIVE);
  int*   ec3flag = (int*)(ws + OFF_EC3F);
  int*   ca1flag = (int*)(ws + OFF_CA1F);
  int*   drvflag = (int*)(ws + OFF_DRVF);
  int*   grpmask = (int*)(ws + OFF_GRP);
  int*   grpcnt  = (int*)(ws + OFF_GRP + 512);
  const int fbase = bi * 32;

  // ---- post group membership (XCD id), agent scope ----
  if (tid == 0) {
    int xcc;
    asm volatile("s_getreg_b32 %0, hwreg(HW_REG_XCC_ID)" : "=s"(xcc));
    __hip_atomic_fetch_or(&grpmask[bi], 1 << (xcc & 31), __ATOMIC_RELAXED, __HIP_MEMORY_SCOPE_AGENT);
    __hip_atomic_fetch_add(&grpcnt[bi], 1, __ATOMIC_RELAXED, __HIP_MEMORY_SCOPE_AGENT);
  }

  // ---- weights -> LDS, bf16, transposed to [n_local][k] ----
  {
    const int c = tid & 31;
    for (int k = tid >> 5; k < FEAT; k += 8) {
      w1l[c * WPAD + k] = (short)f2bf(wec3ca1[k * FEAT + C + c]);
      w2l[c * WPAD + k] = (short)f2bf(wca1ec5[k * FEAT + C + c]);
    }
  }

  // ---- resolve group XCD-uniformity (bounded; cap -> uni=false fallback) ----
  if (tid == 0) {
    flag_wait(&grpcnt[bi], 32);
    int cnt = flag_peek(&grpcnt[bi]);
    int mv  = __hip_atomic_load(&grpmask[bi], __ATOMIC_RELAXED, __HIP_MEMORY_SCOPE_AGENT);
    unil[0] = (cnt >= 32 && __popc(mv) == 1) ? 1 : 0;
  }
  __syncthreads();
  const bool uni = (unil[0] != 0);

  // ---- per-thread element mapping: 1 row x 4 consecutive cols ----
  const int r  = tid >> 3;
  const int c0 = (tid & 7) * 4;
  const int rg = R + r;
  const int cg = C + c0;
  const size_t stoff = (size_t)(((cg >> 3) * 32 + r) * 8 + (c0 & 7));
  const size_t gbase = (size_t)bi * GSTRIDE;
  const int lane = tid & 63, wv = tid >> 6;

  const fx4 biasv  = *(const fx4*)(ca1bias + cg);
  const fx4 wact01 = *(const fx4*)(wca1act + cg * 2);
  const fx4 wact23 = *(const fx4*)(wca1act + cg * 2 + 4);
  fx4 ec3v = *(const fx4*)(ec3_last + (size_t)rg * FEAT + cg);
  fx4 ec5v = *(const fx4*)(ec5_last + (size_t)rg * FEAT + cg);
  fx4 ca1v = 0.0f;

  // ---- publish initial ec3 (flag counts waves: target 4*(t+1)) ----
  ex_store(ec3buf + gbase + stoff, packbf4(ec3v), uni);
  VM_DRAIN();
  if (lane == 0) flag_add(&ec3flag[fbase + nj]);

  // ---- drive precompute: t === bi (mod 8), cols C..C+31 (always LLC path) ----
  {
    float* dred = red4;
    const int g = tid >> 5, n = tid & 31;
    for (int t = bi; t < NSTEP; t += 8) {
      float part = 0.0f;
      const float tf = (float)t;
      for (int c = g * 128; c < g * 128 + 128; ++c) {
        float d = (float)c * (100.0f / 1023.0f) - tf;
        part += __expf(d * d * -0.02f) * wca3ca1[c * FEAT + C + n];
      }
      __syncthreads();
      dred[g * 32 + n] = part;
      __syncthreads();
      if (g == 0) {
        float s = 0.0f;
#pragma unroll
        for (int gg = 0; gg < 8; ++gg) s += dred[gg * 32 + n];
        llc_store_f32(driveg + t * FEAT + C + n, s);
      }
    }
    VM_DRAIN();
    __syncthreads();
    if (tid == 0) {
      flag_add(&drvflag[nj]);
      flag_wait(&drvflag[nj], 8);
    }
    __syncthreads();
    for (int i = tid; i < NSTEP * 32; i += 256) {
      float v;
      asm volatile("global_load_dword %0, %1, off sc0 sc1"
                   : "=v"(v) : "v"(driveg + (i >> 5) * FEAT + C + (i & 31)) : "memory");
      asm volatile("s_waitcnt vmcnt(0)" : "+v"(v) :: "memory");
      drvl[i] = v;
    }
    __syncthreads();
  }

  // =================== main recurrence ===================
  for (int t = 0; t < NSTEP; ++t) {
    const size_t par = (size_t)(t & 1) * PSTRIDE;
    const int tgt = 4 * (t + 1);

    // ---- phase 1: ca1 = relu(drive*(1+sig(ec3@w1)) - bias) ----
    // wave wv's K-slice depends only on producers nj in [8wv, 8wv+8)
    if (lane < 8) flag_wait(&ec3flag[fbase + 8 * wv + lane], tgt);
    if (uni) gemm_phase<true >(ec3buf + par + gbase, w1l, red4, tid);
    else     gemm_phase<false>(ec3buf + par + gbase, w1l, red4, tid);
    __syncthreads();                                  // partials ready

    {
      const int e0 = 4 * tid;
      fx4 p0 = *(const fx4*)(red4 + e0);
      fx4 p1 = *(const fx4*)(red4 + 1024 + e0);
      fx4 p2 = *(const fx4*)(red4 + 2048 + e0);
      fx4 p3 = *(const fx4*)(red4 + 3072 + e0);
      const fx4 dv = *(const fx4*)(drvl + t * 32 + c0);
#pragma unroll
      for (int j = 0; j < 4; ++j) {
        float dot = (p0[j] + p1[j]) + (p2[j] + p3[j]);
        float v = dv[j] * (1.0f + sigm(dot)) - biasv[j];
        ca1v[j] = fmaxf(v, 0.0f);
      }
      ex_store(ca1buf + par + gbase + stoff, packbf4(ca1v), uni);
      if (rg == 0) *(fx4*)(out + O_CAH + t * FEAT + cg) = ca1v;
    }
    VM_DRAIN();
    if (lane == 0) flag_add(&ca1flag[fbase + nj]);
    __syncthreads();                                  // red4 reuse protection

    // ---- phase 2: ec5 += ca1@w2 ; squash ; ec3 = ec5*ec3 ; cue mask ----
    if (lane < 8) flag_wait(&ca1flag[fbase + 8 * wv + lane], tgt);
    if (uni) gemm_phase<true >(ca1buf + par + gbase, w2l, red4, tid);
    else     gemm_phase<false>(ca1buf + par + gbase, w2l, red4, tid);
    __syncthreads();                                  // partials ready

    {
      const int e0 = 4 * tid;
      fx4 p0 = *(const fx4*)(red4 + e0);
      fx4 p1 = *(const fx4*)(red4 + 1024 + e0);
      fx4 p2 = *(const fx4*)(red4 + 2048 + e0);
      fx4 p3 = *(const fx4*)(red4 + 3072 + e0);
#pragma unroll
      for (int j = 0; j < 4; ++j) {
        float e5 = ec5v[j] + ((p0[j] + p1[j]) + (p2[j] + p3[j]));  // 10*TS = 1.0
        e5 = 0.69f + 0.3f * sigm(4.0f * (e5 - 0.3f));
        ec5v[j] = e5;
        ec3v[j] = e5 * ec3v[j];
      }
      if (t == 16 || t == 24) {
        const int s = (t == 24) ? 1 : 0;
        i32x4 m = *(const i32x4*)(cue + (size_t)rg * 2048 + s * 1024 + cg);
#pragma unroll
        for (int j = 0; j < 4; ++j)
          if (m[j]) ec3v[j] = 0.4f * ec3v[j] + 0.6f;
      }
      if (rg == 0) {
        *(fx4*)(out + O_E3H + t * FEAT + cg) = ec3v;
        *(fx4*)(out + O_E5H + t * FEAT + cg) = ec5v;
      }
      if (t < NSTEP - 1) {
        const size_t parn = (size_t)((t + 1) & 1) * PSTRIDE;
        ex_store(ec3buf + parn + gbase + stoff, packbf4(ec3v), uni);
      }
    }
    VM_DRAIN();
    if (lane == 0 && t < NSTEP - 1) flag_add(&ec3flag[fbase + nj]);
    __syncthreads();                                  // red4 reuse protection
  }

  // ---- epilogue: finals + actCell ----
  float* ared = red4;
  if (tid < 64) ared[tid] = 0.0f;
  __syncthreads();
  {
    float p0 = ca1v[0] * wact01[0] + ca1v[1] * wact01[2] +
               ca1v[2] * wact23[0] + ca1v[3] * wact23[2];
    float p1 = ca1v[0] * wact01[1] + ca1v[1] * wact01[3] +
               ca1v[2] * wact23[1] + ca1v[3] * wact23[3];
    atomicAdd(&ared[r * 2 + 0], p0);
    atomicAdd(&ared[r * 2 + 1], p1);
  }
  *(fx4*)(out + O_E3 + (size_t)rg * FEAT + cg) = ec3v;
  *(fx4*)(out + O_E5 + (size_t)rg * FEAT + cg) = ec5v;
  *(fx4*)(out + O_CA + (size_t)rg * FEAT + cg) = ca1v;
  __syncthreads();
  if (tid < 64) {
    float v = ared[tid];
    if (nj == 0) v += actbias[tid & 1];
    atomicAdd(&out[O_ACT + (R + (tid >> 1)) * 2 + (tid & 1)], v);
  }
}

extern "C" void kernel_launch(void* const* d_in, const int* in_sizes, int n_in,
                              void* d_out, int out_size, void* d_ws, size_t ws_size,
                              hipStream_t stream) {
  (void)in_sizes; (void)n_in; (void)out_size;
  if (ws_size < WS_NEED) return;

  const int*   cue      = (const int*)  d_in[0];
  const float* ec3_last = (const float*)d_in[1];
  const float* ec5_last = (const float*)d_in[2];
  // d_in[3] = ca1_last: dead in the reference (overwritten before use)
  const float* ca1bias  = (const float*)d_in[4];
  const float* wca3ca1  = (const float*)d_in[5];
  const float* wec3ca1  = (const float*)d_in[6];
  const float* wca1ec5  = (const float*)d_in[7];
  const float* wca1act  = (const float*)d_in[8];
  const float* actbias  = (const float*)d_in[9];

  char* ws = (char*)d_ws;
  hipMemsetAsync(ws + OFF_EC3F, 0, 4 * 4096, stream);   // flags + rendezvous start at 0
  hipMemsetAsync(d_out, 0, 512 * sizeof(float), stream);

  hipFuncSetAttribute(reinterpret_cast<const void*>(hpcrnn_kernel),
                      hipFuncAttributeMaxDynamicSharedMemorySize, LDS_TOTAL);

  hipLaunchKernelGGL(hpcrnn_kernel, dim3(256), dim3(256), LDS_TOTAL, stream,
                     cue, ec3_last, ec5_last, ca1bias, wca3ca1, wec3ca1,
                     wca1ec5, wca1act, actbias, (float*)d_out, ws);
}

// Round 7
// 739.736 us; speedup vs baseline: 3.4659x; 1.0319x over previous
//
#include <hip/hip_runtime.h>
#include <stdint.h>

// ---------------- problem constants ----------------
#define NSTEP 100
#define BSZ   256
#define FEAT  1024
#define SPIN_CAP (1 << 22)

typedef __attribute__((ext_vector_type(8)))  short short8;
typedef __attribute__((ext_vector_type(4)))  float fx4;
typedef __attribute__((ext_vector_type(16))) float fx16;
typedef __attribute__((ext_vector_type(2)))  unsigned int u32x2;
typedef __attribute__((ext_vector_type(4)))  int i32x4;

// ---------------- workspace layout (bytes) ----------------
// Exchange: parity-double-buffered, 8 groups x (32 rows x 1024 cols) bf16.
// DATA plane: XCD-L2-local (sc0) when the whole group shares an XCD (runtime
// verified via HW_REG_XCC_ID rendezvous; R5-proven); else LLC-coherent (sc1).
// CONTROL plane: ALWAYS agent-scope atomics at the LLC (R3/R5-proven; the two
// attempts to move flags into the XCD L2 both hung -> abandoned).
// Flags count producer WAVES: wave publishes after draining ITS rows (vmcnt0),
// consumer target 4*(t+1).
// Within a group, element (local row m, col c) lives at short index
//   ((c>>3)*32 + m)*8 + (c&7)   (consumer A-loads fully contiguous).
#define OFF_EC3   0u
#define OFF_CA1   (1u << 20)
#define OFF_DRIVE (2u << 20)
#define OFF_EC3F  (OFF_DRIVE + (512u << 10))
#define OFF_CA1F  (OFF_EC3F + 4096u)
#define OFF_DRVF  (OFF_CA1F + 4096u)
#define OFF_GRP   (OFF_DRVF + 4096u)   // grpmask[8] @+0, grpcnt[8] @+512
#define WS_NEED   (OFF_GRP + 4096u)

#define GSTRIDE 32768                  // shorts per group (32*1024)
#define PSTRIDE (8 * GSTRIDE)          // shorts per parity buffer

// ---------------- output layout (float elems) ----------------
#define O_ACT 0
#define O_E3H 512
#define O_E5H (512 + 102400)
#define O_CAH (512 + 204800)
#define O_E3  (512 + 307200)
#define O_E5  (O_E3 + 262144)
#define O_CA  (O_E5 + 262144)

// ---------------- LDS layout (bytes) ----------------
// Weights CHUNKED like the A buffer: granule g=(k>>3), short idx ((g*32+n)*8+(k&7))
// -> consumer B-reads are conflict-free ds_read_b128 (kills the 1.57M conflicts).
#define LDS_W1    0
#define LDS_W2    65536
#define LDS_RED4  131072               // 4*1024 f32 = 16384
#define LDS_DRV   147456               // 100*32 f32 = 12800
#define LDS_UNI   160256               // 1 int
#define LDS_TOTAL 160272               // <= 163840

__device__ __forceinline__ unsigned short f2bf(float x) {
  uint32_t u = __builtin_bit_cast(uint32_t, x);
  uint32_t r = (u + 0x7FFFu + ((u >> 16) & 1u)) >> 16;   // RNE
  return (unsigned short)r;
}
__device__ __forceinline__ float sigm(float x) { return 1.0f / (1.0f + __expf(-x)); }

#define VM_DRAIN() asm volatile("s_waitcnt vmcnt(0)" ::: "memory")

// data-plane store: uni -> dirty line in shared XCD L2; else -> LLC coherent
__device__ __forceinline__ void ex_store(void* p, u32x2 v, bool uni) {
  if (uni) asm volatile("global_store_dwordx2 %0, %1, off sc0"     :: "v"(p), "v"(v) : "memory");
  else     asm volatile("global_store_dwordx2 %0, %1, off sc0 sc1" :: "v"(p), "v"(v) : "memory");
}
__device__ __forceinline__ void llc_store_f32(float* p, float v) {
  asm volatile("global_store_dword %0, %1, off sc0 sc1" :: "v"(p), "v"(v) : "memory");
}
// control plane: agent scope at the LLC, always
__device__ __forceinline__ void flag_add(int* p) {
  __hip_atomic_fetch_add(p, 1, __ATOMIC_RELAXED, __HIP_MEMORY_SCOPE_AGENT);
}
__device__ __forceinline__ int flag_peek(const int* p) {
  return __hip_atomic_load(p, __ATOMIC_RELAXED, __HIP_MEMORY_SCOPE_AGENT);
}
__device__ __forceinline__ void flag_wait(const int* p, int tgt) {
  int sp = 0;
  while (flag_peek(p) < tgt) {
    __builtin_amdgcn_s_sleep(1);
    if (++sp > SPIN_CAP) break;
  }
}

__device__ __forceinline__ u32x2 packbf4(fx4 v) {
  u32x2 r;
  r[0] = (uint32_t)f2bf(v[0]) | ((uint32_t)f2bf(v[1]) << 16);
  r[1] = (uint32_t)f2bf(v[2]) | ((uint32_t)f2bf(v[3]) << 16);
  return r;
}

// 32x32 out-tile partials; wave w handles K-slice [256w,256w+256).
// A (global, chunked, 1KB contiguous per load inst); B (LDS, chunked identically:
// operand [n=m][k=w*256+i*16+h*8+j] lives at short w*8192+i*512+h*256+m*8 -> the
// same (32w+h)*256 + m*8 + i*512 indexing as A). Partials to red4[w][row*32+col]
// (C: col=lane&31, row=(reg&3)+8*(reg>>2)+4*(lane>>5)).
template <bool UNI>
__device__ __forceinline__ void gemm_phase(const short* __restrict__ abuf,
                                           const short* __restrict__ wl,
                                           float* __restrict__ red4, int tid) {
  const int lane = tid & 63, w = tid >> 6;
  const int m = lane & 31, h = lane >> 5;
  const short* ap = abuf + (32 * w + h) * 256 + m * 8;
  const short* bp = wl + (32 * w + h) * 256 + m * 8;
  short8 A[16];
  if (UNI) {
#pragma unroll
    for (int i = 0; i < 16; ++i)
      asm volatile("global_load_dwordx4 %0, %1, off sc0"
                   : "=v"(A[i]) : "v"(ap + i * 512) : "memory");
  } else {
#pragma unroll
    for (int i = 0; i < 16; ++i)
      asm volatile("global_load_dwordx4 %0, %1, off sc0 sc1"
                   : "=v"(A[i]) : "v"(ap + i * 512) : "memory");
  }
  asm volatile("s_waitcnt vmcnt(0)"
               : "+v"(A[0]), "+v"(A[1]), "+v"(A[2]), "+v"(A[3]),
                 "+v"(A[4]), "+v"(A[5]), "+v"(A[6]), "+v"(A[7]),
                 "+v"(A[8]), "+v"(A[9]), "+v"(A[10]), "+v"(A[11]),
                 "+v"(A[12]), "+v"(A[13]), "+v"(A[14]), "+v"(A[15])
               :: "memory");
  fx16 acc = 0.0f;
#pragma unroll
  for (int i = 0; i < 16; ++i) {
    short8 b = *(const short8*)(bp + i * 512);
    acc = __builtin_amdgcn_mfma_f32_32x32x16_bf16(A[i], b, acc, 0, 0, 0);
  }
#pragma unroll
  for (int i = 0; i < 16; ++i)
    red4[w * 1024 + ((i & 3) + 8 * (i >> 2) + 4 * h) * 32 + m] = acc[i];
}

extern "C" __global__ void __launch_bounds__(256)
hpcrnn_kernel(const int* __restrict__ cue,
              const float* __restrict__ ec3_last,
              const float* __restrict__ ec5_last,
              const float* __restrict__ ca1bias,
              const float* __restrict__ wca3ca1,
              const float* __restrict__ wec3ca1,
              const float* __restrict__ wca1ec5,
              const float* __restrict__ wca1act,
              const float* __restrict__ actbias,
              float* __restrict__ out,
              char* __restrict__ ws)
{
  extern __shared__ __attribute__((aligned(16))) char lds[];
  short* w1l  = (short*)(lds + LDS_W1);
  short* w2l  = (short*)(lds + LDS_W2);
  float* red4 = (float*)(lds + LDS_RED4);
  float* drvl = (float*)(lds + LDS_DRV);
  int*   unil = (int*)(lds + LDS_UNI);

  const int tid = threadIdx.x;
  const int bi  = blockIdx.x & 7;    // batch group; %8 == XCD residue (round-robin heuristic)
  const int nj  = blockIdx.x >> 3;   // N chunk (32 cols)
  const int R   = bi * 32, C = nj * 32;

  short* ec3buf = (short*)(ws + OFF_EC3);
  short* ca1buf = (short*)(ws + OFF_CA1);
  float* driveg = (float*)(ws + OFF_DRIVE);
  int*   ec3flag = (int*)(ws + OFF_EC3F);
  int*   ca1flag = (int*)(ws + OFF_CA1F);
  int*   drvflag = (int*)(ws + OFF_DRVF);
  int*   grpmask = (int*)(ws + OFF_GRP);
  int*   grpcnt  = (int*)(ws + OFF_GRP + 512);
  const int fbase = bi * 32;

  // ---- post group membership (XCD id), agent scope ----
  if (tid == 0) {
    int xcc;
    asm volatile("s_getreg_b32 %0, hwreg(HW_REG_XCC_ID)" : "=s"(xcc));
    __hip_atomic_fetch_or(&grpmask[bi], 1 << (xcc & 31), __ATOMIC_RELAXED, __HIP_MEMORY_SCOPE_AGENT);
    __hip_atomic_fetch_add(&grpcnt[bi], 1, __ATOMIC_RELAXED, __HIP_MEMORY_SCOPE_AGENT);
  }

  // ---- weights -> LDS, bf16, CHUNKED [g=(k>>3)][n][k&7] ----
  {
    const int c = tid & 31;
    for (int k = tid >> 5; k < FEAT; k += 8) {
      const int idx = ((k >> 3) * 32 + c) * 8 + (k & 7);
      w1l[idx] = (short)f2bf(wec3ca1[k * FEAT + C + c]);
      w2l[idx] = (short)f2bf(wca1ec5[k * FEAT + C + c]);
    }
  }

  // ---- resolve group XCD-uniformity (bounded; cap -> uni=false fallback) ----
  if (tid == 0) {
    flag_wait(&grpcnt[bi], 32);
    int cnt = flag_peek(&grpcnt[bi]);
    int mv  = __hip_atomic_load(&grpmask[bi], __ATOMIC_RELAXED, __HIP_MEMORY_SCOPE_AGENT);
    unil[0] = (cnt >= 32 && __popc(mv) == 1) ? 1 : 0;
  }
  __syncthreads();
  const bool uni = (unil[0] != 0);

  // ---- per-thread element mapping: 1 row x 4 consecutive cols ----
  const int r  = tid >> 3;
  const int c0 = (tid & 7) * 4;
  const int rg = R + r;
  const int cg = C + c0;
  const size_t stoff = (size_t)(((cg >> 3) * 32 + r) * 8 + (c0 & 7));
  const size_t gbase = (size_t)bi * GSTRIDE;
  const int lane = tid & 63, wv = tid >> 6;

  const fx4 biasv  = *(const fx4*)(ca1bias + cg);
  const fx4 wact01 = *(const fx4*)(wca1act + cg * 2);
  const fx4 wact23 = *(const fx4*)(wca1act + cg * 2 + 4);
  fx4 ec3v = *(const fx4*)(ec3_last + (size_t)rg * FEAT + cg);
  fx4 ec5v = *(const fx4*)(ec5_last + (size_t)rg * FEAT + cg);
  fx4 ca1v = 0.0f;

  // ---- publish initial ec3 (per-wave: wave drains its rows, lane0 adds) ----
  ex_store(ec3buf + gbase + stoff, packbf4(ec3v), uni);
  VM_DRAIN();
  if (lane == 0) flag_add(&ec3flag[fbase + nj]);

  // ---- drive precompute: t === bi (mod 8), cols C..C+31 (always LLC path) ----
  {
    float* dred = red4;
    const int g = tid >> 5, n = tid & 31;
    for (int t = bi; t < NSTEP; t += 8) {
      float part = 0.0f;
      const float tf = (float)t;
      for (int c = g * 128; c < g * 128 + 128; ++c) {
        float d = (float)c * (100.0f / 1023.0f) - tf;
        part += __expf(d * d * -0.02f) * wca3ca1[c * FEAT + C + n];
      }
      __syncthreads();
      dred[g * 32 + n] = part;
      __syncthreads();
      if (g == 0) {
        float s = 0.0f;
#pragma unroll
        for (int gg = 0; gg < 8; ++gg) s += dred[gg * 32 + n];
        llc_store_f32(driveg + t * FEAT + C + n, s);
      }
    }
    VM_DRAIN();
    __syncthreads();
    if (tid == 0) {
      flag_add(&drvflag[nj]);
      flag_wait(&drvflag[nj], 8);
    }
    __syncthreads();
    for (int i = tid; i < NSTEP * 32; i += 256) {
      float v;
      asm volatile("global_load_dword %0, %1, off sc0 sc1"
                   : "=v"(v) : "v"(driveg + (i >> 5) * FEAT + C + (i & 31)) : "memory");
      asm volatile("s_waitcnt vmcnt(0)" : "+v"(v) :: "memory");
      drvl[i] = v;
    }
    __syncthreads();
  }

  // =================== main recurrence ===================
  for (int t = 0; t < NSTEP; ++t) {
    const size_t par = (size_t)(t & 1) * PSTRIDE;
    const int tgt = 4 * (t + 1);

    // ---- phase 1: ca1 = relu(drive*(1+sig(ec3@w1)) - bias) ----
    // wave wv's K-slice depends only on producers nj' in [8wv, 8wv+8)
    if (lane < 8) flag_wait(&ec3flag[fbase + 8 * wv + lane], tgt);
    if (uni) gemm_phase<true >(ec3buf + par + gbase, w1l, red4, tid);
    else     gemm_phase<false>(ec3buf + par + gbase, w1l, red4, tid);
    __syncthreads();                                  // partials ready

    {
      const int e0 = 4 * tid;
      fx4 p0 = *(const fx4*)(red4 + e0);
      fx4 p1 = *(const fx4*)(red4 + 1024 + e0);
      fx4 p2 = *(const fx4*)(red4 + 2048 + e0);
      fx4 p3 = *(const fx4*)(red4 + 3072 + e0);
      const fx4 dv = *(const fx4*)(drvl + t * 32 + c0);
#pragma unroll
      for (int j = 0; j < 4; ++j) {
        float dot = (p0[j] + p1[j]) + (p2[j] + p3[j]);
        float v = dv[j] * (1.0f + sigm(dot)) - biasv[j];
        ca1v[j] = fmaxf(v, 0.0f);
      }
      ex_store(ca1buf + par + gbase + stoff, packbf4(ca1v), uni);
    }
    VM_DRAIN();                                       // this wave's rows in L2/LLC
    if (lane == 0) flag_add(&ca1flag[fbase + nj]);    // EARLY per-wave publish
    if (rg == 0) *(fx4*)(out + O_CAH + t * FEAT + cg) = ca1v;   // off critical path
    __syncthreads();                                  // red4 reuse protection

    // ---- phase 2: ec5 += ca1@w2 ; squash ; ec3 = ec5*ec3 ; cue mask ----
    if (lane < 8) flag_wait(&ca1flag[fbase + 8 * wv + lane], tgt);
    if (uni) gemm_phase<true >(ca1buf + par + gbase, w2l, red4, tid);
    else     gemm_phase<false>(ca1buf + par + gbase, w2l, red4, tid);
    __syncthreads();                                  // partials ready

    {
      const int e0 = 4 * tid;
      fx4 p0 = *(const fx4*)(red4 + e0);
      fx4 p1 = *(const fx4*)(red4 + 1024 + e0);
      fx4 p2 = *(const fx4*)(red4 + 2048 + e0);
      fx4 p3 = *(const fx4*)(red4 + 3072 + e0);
#pragma unroll
      for (int j = 0; j < 4; ++j) {
        float e5 = ec5v[j] + ((p0[j] + p1[j]) + (p2[j] + p3[j]));  // 10*TS = 1.0
        e5 = 0.69f + 0.3f * sigm(4.0f * (e5 - 0.3f));
        ec5v[j] = e5;
        ec3v[j] = e5 * ec3v[j];
      }
      if (t == 16 || t == 24) {
        const int s = (t == 24) ? 1 : 0;
        i32x4 m = *(const i32x4*)(cue + (size_t)rg * 2048 + s * 1024 + cg);
#pragma unroll
        for (int j = 0; j < 4; ++j)
          if (m[j]) ec3v[j] = 0.4f * ec3v[j] + 0.6f;
      }
      if (t < NSTEP - 1) {
        const size_t parn = (size_t)((t + 1) & 1) * PSTRIDE;
        ex_store(ec3buf + parn + gbase + stoff, packbf4(ec3v), uni);
      }
    }
    VM_DRAIN();
    if (lane == 0 && t < NSTEP - 1) flag_add(&ec3flag[fbase + nj]);  // EARLY publish
    if (rg == 0) {                                    // off critical path
      *(fx4*)(out + O_E3H + t * FEAT + cg) = ec3v;
      *(fx4*)(out + O_E5H + t * FEAT + cg) = ec5v;
    }
    __syncthreads();                                  // red4 reuse protection
  }

  // ---- epilogue: finals + actCell ----
  float* ared = red4;
  if (tid < 64) ared[tid] = 0.0f;
  __syncthreads();
  {
    float p0 = ca1v[0] * wact01[0] + ca1v[1] * wact01[2] +
               ca1v[2] * wact23[0] + ca1v[3] * wact23[2];
    float p1 = ca1v[0] * wact01[1] + ca1v[1] * wact01[3] +
               ca1v[2] * wact23[1] + ca1v[3] * wact23[3];
    atomicAdd(&ared[r * 2 + 0], p0);
    atomicAdd(&ared[r * 2 + 1], p1);
  }
  *(fx4*)(out + O_E3 + (size_t)rg * FEAT + cg) = ec3v;
  *(fx4*)(out + O_E5 + (size_t)rg * FEAT + cg) = ec5v;
  *(fx4*)(out + O_CA + (size_t)rg * FEAT + cg) = ca1v;
  __syncthreads();
  if (tid < 64) {
    float v = ared[tid];
    if (nj == 0) v += actbias[tid & 1];
    atomicAdd(&out[O_ACT + (R + (tid >> 1)) * 2 + (tid & 1)], v);
  }
}

extern "C" void kernel_launch(void* const* d_in, const int* in_sizes, int n_in,
                              void* d_out, int out_size, void* d_ws, size_t ws_size,
                              hipStream_t stream) {
  (void)in_sizes; (void)n_in; (void)out_size;
  if (ws_size < WS_NEED) return;

  const int*   cue      = (const int*)  d_in[0];
  const float* ec3_last = (const float*)d_in[1];
  const float* ec5_last = (const float*)d_in[2];
  // d_in[3] = ca1_last: dead in the reference (overwritten before use)
  const float* ca1bias  = (const float*)d_in[4];
  const float* wca3ca1  = (const float*)d_in[5];
  const float* wec3ca1  = (const float*)d_in[6];
  const float* wca1ec5  = (const float*)d_in[7];
  const float* wca1act  = (const float*)d_in[8];
  const float* actbias  = (const float*)d_in[9];

  char* ws = (char*)d_ws;
  hipMemsetAsync(ws + OFF_EC3F, 0, 4 * 4096, stream);   // flags + rendezvous start at 0
  hipMemsetAsync(d_out, 0, 512 * sizeof(float), stream);

  hipFuncSetAttribute(reinterpret_cast<const void*>(hpcrnn_kernel),
                      hipFuncAttributeMaxDynamicSharedMemorySize, LDS_TOTAL);

  hipLaunchKernelGGL(hpcrnn_kernel, dim3(256), dim3(256), LDS_TOTAL, stream,
                     cue, ec3_last, ec5_last, ca1bias, wca3ca1, wec3ca1,
                     wca1ec5, wca1act, actbias, (float*)d_out, ws);
}